// Round 2
// baseline (1181.433 us; speedup 1.0000x reference)
//
#include <hip/hip_runtime.h>

// ParallelNCA: 64 grouped tiny MLPs over 3x3 perception, f32 baseline.
// B=16, M=64, C=16, Hd=128, H=W=32. Group g uses concatenated-perception
// channels [g*144, g*144+144): ch -> shift s = ch>>10, model-chan mc = ch&1023.

constexpr int Bn  = 16;
constexpr int Mn  = 64;
constexpr int Cn  = 16;
constexpr int Hd  = 128;
constexpr int Hh  = 32;
constexpr int Wh  = 32;
constexpr int K9  = 144;   // 9*C
constexpr int MCn = 1024;  // M*C
constexpr int Ts  = 64;    // spatial tile (2 rows)
constexpr int NT  = 256;   // threads per block

__global__ __launch_bounds__(NT, 2)
void nca_f32_kernel(const float* __restrict__ x,
                    const float* __restrict__ w1,
                    const float* __restrict__ b1,
                    const float* __restrict__ w2,
                    const float* __restrict__ b2,
                    float* __restrict__ out)
{
    // uni: phase01 = perception Ps[144][64] (36864B); phase2 = hdnT[64][132] (33792B)
    __shared__ __align__(16) float uni[K9 * Ts];
    __shared__ __align__(16) float w1s[16][Hd + 4];  // k-chunk transposed, padded
    __shared__ __align__(16) float w2s[Cn][Hd];

    float (*Ps)[Ts]      = (float(*)[Ts])uni;
    float (*hdnT)[Hd + 4] = (float(*)[Hd + 4])uni;

    const int tid  = threadIdx.x;
    const int tile = blockIdx.x & 15;          // 16 tiles of 64 pixels
    const int m    = (blockIdx.x >> 4) & 63;
    const int b    = blockIdx.x >> 10;
    const int pbase = tile * Ts;

    // ---------------- Phase 0: gather perception tile into LDS ----------------
    for (int e = tid; e < K9 * Ts; e += NT) {
        const int k  = e >> 6;        // /Ts
        const int t  = e & 63;
        const int ch = m * K9 + k;    // concatenated-perception channel
        const int s  = ch >> 10;      // shift index 0..8
        const int mc = ch & 1023;     // source channel in x
        int dr = 0, dc = 0;
        if (s > 0) {                  // s=1..8 -> (r,c) skipping (0,0)
            const int q = (s - 1) < 4 ? (s - 1) : s;
            dr = q / 3 - 1;
            dc = q % 3 - 1;
        }
        const int p = pbase + t;
        const int h = (p >> 5) + dr;
        const int w = (p & 31) + dc;
        float v = 0.f;
        if ((unsigned)h < 32u && (unsigned)w < 32u)
            v = x[((b * MCn + mc) * Hh + h) * Wh + w];
        Ps[k][t] = v;
    }
    __syncthreads();

    // ---------------- Phase 1: hdn = relu(w1 @ P + b1), 128x64x144 ----------------
    const int tg = tid & 15;  const int t0 = tg * 4;   // 4 pixels / thread
    const int dg = tid >> 4;  const int d0 = dg * 8;   // 8 hidden / thread

    float acc[8][4];
    #pragma unroll
    for (int j = 0; j < 8; ++j)
        #pragma unroll
        for (int u = 0; u < 4; ++u) acc[j][u] = 0.f;

    for (int kc = 0; kc < 9; ++kc) {
        // stage w1[:, kc*16 .. kc*16+15] transposed: w1s[i][d]
        for (int e = tid; e < 16 * Hd; e += NT) {
            const int i = e & 15;
            const int d = e >> 4;
            w1s[i][d] = w1[(m * Hd + d) * K9 + kc * 16 + i];
        }
        __syncthreads();
        #pragma unroll
        for (int i = 0; i < 16; ++i) {
            const int k = kc * 16 + i;
            const float4 p4 = *(const float4*)&Ps[k][t0];
            const float4 wa = *(const float4*)&w1s[i][d0];
            const float4 wb = *(const float4*)&w1s[i][d0 + 4];
            const float pv[4] = {p4.x, p4.y, p4.z, p4.w};
            const float wv[8] = {wa.x, wa.y, wa.z, wa.w, wb.x, wb.y, wb.z, wb.w};
            #pragma unroll
            for (int j = 0; j < 8; ++j)
                #pragma unroll
                for (int u = 0; u < 4; ++u)
                    acc[j][u] = fmaf(wv[j], pv[u], acc[j][u]);
        }
        __syncthreads();   // protect w1s before next-chunk staging (and Ps reuse)
    }

    // bias + relu, store hdn transposed [t][d] into uni (Ps no longer needed)
    float bv[8];
    #pragma unroll
    for (int j = 0; j < 8; ++j) bv[j] = b1[m * Hd + d0 + j];
    #pragma unroll
    for (int u = 0; u < 4; ++u) {
        float hreg[8];
        #pragma unroll
        for (int j = 0; j < 8; ++j) hreg[j] = fmaxf(acc[j][u] + bv[j], 0.f);
        *(float4*)&hdnT[t0 + u][d0]     = *(const float4*)&hreg[0];
        *(float4*)&hdnT[t0 + u][d0 + 4] = *(const float4*)&hreg[4];
    }
    // stage w2 (16x128) while hdn writes land (disjoint LDS regions)
    for (int e = tid; e < Cn * Hd; e += NT) {
        const int d = e & 127;
        const int c = e >> 7;
        w2s[c][d] = w2[(m * Cn + c) * Hd + d];
    }
    __syncthreads();

    // ---------------- Phase 2: dx = w2 @ hdn + b2; out = x + dx ----------------
    const int t2 = tid & 63;
    const int c0 = (tid >> 6) * 4;     // 4 out-channels / thread
    float acc2[4] = {0.f, 0.f, 0.f, 0.f};
    #pragma unroll 8
    for (int d = 0; d < Hd; d += 4) {
        const float4 hv = *(const float4*)&hdnT[t2][d];
        #pragma unroll
        for (int j = 0; j < 4; ++j) {
            const float4 wv = *(const float4*)&w2s[c0 + j][d];
            acc2[j] = fmaf(hv.x, wv.x, acc2[j]);
            acc2[j] = fmaf(hv.y, wv.y, acc2[j]);
            acc2[j] = fmaf(hv.z, wv.z, acc2[j]);
            acc2[j] = fmaf(hv.w, wv.w, acc2[j]);
        }
    }
    const int p = pbase + t2;
    const int h = p >> 5;
    const int w = p & 31;
    #pragma unroll
    for (int j = 0; j < 4; ++j) {
        const int ch  = m * Cn + c0 + j;
        const int idx = ((b * MCn + ch) * Hh + h) * Wh + w;
        out[idx] = x[idx] + acc2[j] + b2[ch];
    }
}

extern "C" void kernel_launch(void* const* d_in, const int* in_sizes, int n_in,
                              void* d_out, int out_size, void* d_ws, size_t ws_size,
                              hipStream_t stream)
{
    const float* x  = (const float*)d_in[0];
    const float* w1 = (const float*)d_in[1];
    const float* b1 = (const float*)d_in[2];
    const float* w2 = (const float*)d_in[3];
    const float* b2 = (const float*)d_in[4];
    float* out = (float*)d_out;

    const int grid = Bn * Mn * (Hh * Wh / Ts);  // 16*64*16 = 16384
    nca_f32_kernel<<<grid, NT, 0, stream>>>(x, w1, b1, w2, b2, out);
}

// Round 3
// 411.773 us; speedup vs baseline: 2.8691x; 2.8691x over previous
//
#include <hip/hip_runtime.h>

// ParallelNCA on MFMA: 64 grouped MLPs (144->128->16) over 3x3 perception.
// Per block: (m, 128-pixel tile). GEMM1 128x128x160(bf16), GEMM2 16x128x128.
// Pt stride 336B and hdnT stride 272B: odd 16B-slot counts -> <=2-way LDS
// bank conflicts for both b128 reads and strided writes (no XOR needed).

typedef __attribute__((ext_vector_type(8))) short short8;   // 8 bf16 frag
typedef __attribute__((ext_vector_type(4))) float f32x4;    // MFMA acc

constexpr int Bn  = 16;
constexpr int Mn  = 64;
constexpr int Cn  = 16;
constexpr int Hd  = 128;
constexpr int K9  = 144;
constexpr int MCn = 1024;
constexpr int NP  = 128;    // pixels per block
constexpr int KP  = 160;    // K padded to 5 MFMA k-steps
constexpr int PT_STRIDE = 336;  // bytes per pixel row of Pt (21 slots, odd)
constexpr int HT_STRIDE = 272;  // bytes per pixel row of hdnT (17 slots, odd)
constexpr int NT  = 256;

__device__ __forceinline__ ushort f2bf(float f) {
    union { float f; uint u; } v; v.f = f;
    const uint u = v.u;
    return (ushort)((u + 0x7fffu + ((u >> 16) & 1u)) >> 16);   // RNE
}

__global__ __launch_bounds__(NT, 2)
void nca_mfma(const float* __restrict__ x,  const float* __restrict__ w1,
              const float* __restrict__ b1, const float* __restrict__ w2,
              const float* __restrict__ b2, float* __restrict__ out)
{
    __shared__ __align__(16) char PtL[NP * PT_STRIDE];  // 43008 B, bf16 perception
    __shared__ __align__(16) char HtL[NP * HT_STRIDE];  // 34816 B, bf16 hidden

    const int tid  = threadIdx.x;
    const int lane = tid & 63;
    const int wid  = tid >> 6;      // wave 0..3
    const int lr   = lane & 15;     // MFMA row/col lane index
    const int lk   = lane >> 4;     // MFMA k-group 0..3

    const int m  = blockIdx.x >> 7;         // model 0..63
    const int pt = blockIdx.x & 127;        // pixel tile 0..127
    const int b  = pt >> 3;                 // batch 0..15
    const int p0 = (pt & 7) * NP;           // pixel base within image

    // ---------- w1 prefetch (f32, converted after gather) ----------
    // wave wid owns output rows [wid*32, wid*32+32): 2 row-tiles.
    float4 w1f[2][5][2];
    #pragma unroll
    for (int rt = 0; rt < 2; ++rt) {
        const int row = wid * 32 + rt * 16 + lr;
        const float* wr = w1 + (m * Hd + row) * K9;
        #pragma unroll
        for (int ks = 0; ks < 5; ++ks) {
            const int k0 = ks * 32 + lk * 8;
            if (k0 < K9) {
                w1f[rt][ks][0] = *(const float4*)(wr + k0);
                w1f[rt][ks][1] = *(const float4*)(wr + k0 + 4);
            } else {
                w1f[rt][ks][0] = make_float4(0.f, 0.f, 0.f, 0.f);
                w1f[rt][ks][1] = make_float4(0.f, 0.f, 0.f, 0.f);
            }
        }
    }

    // ---------- gather perception -> Pt[pixel][k] (bf16, k-pairs) ----------
    // wave-chunk mapping: 16 consecutive pixels x 4 k-pairs per 64 lanes
    // -> coalesced 64B global segments AND 2-way-max LDS write conflicts.
    #pragma unroll 1
    for (int it = 0; it < (KP / 2) * NP / NT; ++it) {   // 40 iterations
        const int e     = it * NT + tid;
        const int sub   = e & 63;
        const int chunk = e >> 6;
        const int p     = (chunk & 7) * 16 + (sub & 15);
        const int kp    = (chunk >> 3) * 4 + (sub >> 4);   // k-pair 0..79
        const int gp    = p0 + p;
        const int h = gp >> 5, w = gp & 31;
        uint pack = 0;
        #pragma unroll
        for (int half = 0; half < 2; ++half) {
            const int k = kp * 2 + half;
            float v = 0.f;
            if (k < K9) {
                const int ch = m * K9 + k;   // concatenated-perception channel
                const int s  = ch >> 10;     // shift index 0..8
                const int mc = ch & 1023;    // source channel of x
                int dr = 0, dc = 0;
                if (s > 0) {
                    const int q = (s - 1) < 4 ? (s - 1) : s;
                    const int q3 = q / 3;
                    dr = q3 - 1; dc = q - q3 * 3 - 1;
                }
                const int hh = h + dr, ww = w + dc;
                if (((unsigned)hh < 32u) & ((unsigned)ww < 32u))
                    v = x[((b * MCn + mc) * 32 + hh) * 32 + ww];
            }
            pack |= (uint)f2bf(v) << (16 * half);
        }
        *(uint*)(PtL + p * PT_STRIDE + kp * 4) = pack;
    }
    __syncthreads();

    // ---------- convert w1 -> bf16 A-frags ----------
    short8 a1[2][5];
    #pragma unroll
    for (int rt = 0; rt < 2; ++rt)
        #pragma unroll
        for (int ks = 0; ks < 5; ++ks) {
            short8 t;
            t[0] = (short)f2bf(w1f[rt][ks][0].x); t[1] = (short)f2bf(w1f[rt][ks][0].y);
            t[2] = (short)f2bf(w1f[rt][ks][0].z); t[3] = (short)f2bf(w1f[rt][ks][0].w);
            t[4] = (short)f2bf(w1f[rt][ks][1].x); t[5] = (short)f2bf(w1f[rt][ks][1].y);
            t[6] = (short)f2bf(w1f[rt][ks][1].z); t[7] = (short)f2bf(w1f[rt][ks][1].w);
            a1[rt][ks] = t;
        }

    // ---------- w2 prefetch (completes during GEMM1) ----------
    float4 w2f[4][2];
    #pragma unroll
    for (int ks = 0; ks < 4; ++ks) {
        const float* wr = w2 + (m * Cn + lr) * Hd + ks * 32 + lk * 8;
        w2f[ks][0] = *(const float4*)(wr);
        w2f[ks][1] = *(const float4*)(wr + 4);
    }

    // ---------- GEMM1: hdn = w1 @ P, 128x128x160 ----------
    f32x4 acc[2][8];
    #pragma unroll
    for (int i = 0; i < 2; ++i)
        #pragma unroll
        for (int j = 0; j < 8; ++j) acc[i][j] = (f32x4){0.f, 0.f, 0.f, 0.f};

    #pragma unroll
    for (int ct = 0; ct < 8; ++ct) {
        const int p = ct * 16 + lr;
        const char* base = PtL + p * PT_STRIDE + lk * 16;
        short8 bfrag[5];
        #pragma unroll
        for (int ks = 0; ks < 5; ++ks)
            bfrag[ks] = *(const short8*)(base + ks * 64);
        #pragma unroll
        for (int ks = 0; ks < 5; ++ks) {
            acc[0][ct] = __builtin_amdgcn_mfma_f32_16x16x32_bf16(a1[0][ks], bfrag[ks], acc[0][ct], 0, 0, 0);
            acc[1][ct] = __builtin_amdgcn_mfma_f32_16x16x32_bf16(a1[1][ks], bfrag[ks], acc[1][ct], 0, 0, 0);
        }
    }

    // ---------- bias+relu -> hdnT[pixel][hd] bf16 ----------
    #pragma unroll
    for (int rt = 0; rt < 2; ++rt) {
        const int hd0 = wid * 32 + rt * 16 + lk * 4;   // C/D row = (lane>>4)*4 + reg
        const float4 bs = *(const float4*)(b1 + m * Hd + hd0);
        #pragma unroll
        for (int ct = 0; ct < 8; ++ct) {
            const int p = ct * 16 + lr;                // C/D col = lane&15
            const f32x4 v = acc[rt][ct];
            const uint lo = (uint)f2bf(fmaxf(v[0] + bs.x, 0.f)) |
                            ((uint)f2bf(fmaxf(v[1] + bs.y, 0.f)) << 16);
            const uint hi = (uint)f2bf(fmaxf(v[2] + bs.z, 0.f)) |
                            ((uint)f2bf(fmaxf(v[3] + bs.w, 0.f)) << 16);
            uint2 pk; pk.x = lo; pk.y = hi;
            *(uint2*)(HtL + p * HT_STRIDE + hd0 * 2) = pk;
        }
    }
    __syncthreads();

    // ---------- GEMM2: dx = w2 @ hdn, 16x128x128 ----------
    short8 a2[4];
    #pragma unroll
    for (int ks = 0; ks < 4; ++ks) {
        short8 t;
        t[0] = (short)f2bf(w2f[ks][0].x); t[1] = (short)f2bf(w2f[ks][0].y);
        t[2] = (short)f2bf(w2f[ks][0].z); t[3] = (short)f2bf(w2f[ks][0].w);
        t[4] = (short)f2bf(w2f[ks][1].x); t[5] = (short)f2bf(w2f[ks][1].y);
        t[6] = (short)f2bf(w2f[ks][1].z); t[7] = (short)f2bf(w2f[ks][1].w);
        a2[ks] = t;
    }

    f32x4 acc2[2];
    #pragma unroll
    for (int j = 0; j < 2; ++j) {
        const int ct = wid * 2 + j;           // 4 waves x 2 = 8 col-tiles
        const int p  = ct * 16 + lr;
        const char* base = HtL + p * HT_STRIDE + lk * 16;
        short8 bb[4];
        #pragma unroll
        for (int ks = 0; ks < 4; ++ks)
            bb[ks] = *(const short8*)(base + ks * 64);
        f32x4 a = (f32x4){0.f, 0.f, 0.f, 0.f};
        #pragma unroll
        for (int ks = 0; ks < 4; ++ks)
            a = __builtin_amdgcn_mfma_f32_16x16x32_bf16(a2[ks], bb[ks], a, 0, 0, 0);
        acc2[j] = a;
    }

    // ---------- epilogue: out = x + dx + b2 ----------
    const float4 b2v = *(const float4*)(b2 + m * Cn + lk * 4);
    const float bsv[4] = {b2v.x, b2v.y, b2v.z, b2v.w};
    #pragma unroll
    for (int j = 0; j < 2; ++j) {
        const int ct = wid * 2 + j;
        const int gp = p0 + ct * 16 + lr;
        #pragma unroll
        for (int r = 0; r < 4; ++r) {
            const int c   = lk * 4 + r;
            const int idx = (b * MCn + m * Cn + c) * 1024 + gp;
            out[idx] = x[idx] + acc2[j][r] + bsv[r];
        }
    }
}

extern "C" void kernel_launch(void* const* d_in, const int* in_sizes, int n_in,
                              void* d_out, int out_size, void* d_ws, size_t ws_size,
                              hipStream_t stream)
{
    const float* x  = (const float*)d_in[0];
    const float* w1 = (const float*)d_in[1];
    const float* b1 = (const float*)d_in[2];
    const float* w2 = (const float*)d_in[3];
    const float* b2 = (const float*)d_in[4];
    float* out = (float*)d_out;

    const int grid = Mn * (Bn * 1024 / NP);   // 64 * 128 = 8192
    nca_mfma<<<grid, NT, 0, stream>>>(x, w1, b1, w2, b2, out);
}

// Round 4
// 268.818 us; speedup vs baseline: 4.3949x; 1.5318x over previous
//
#include <hip/hip_runtime.h>

// ParallelNCA on MFMA: 64 grouped MLPs (144->128->16) over 3x3 perception.
// Per block: (m, 128-pixel tile). GEMM1 128x128x160(bf16), GEMM2 16x128x128.
// Round 3 changes vs round 2:
//  - gather restructured: 16-lane group owns a k-pair; per-k setup hoisted,
//    linear pixel sweep, packed b32 LDS writes (VALU ~5x cut).
//  - Pt/Ht LDS union (Ht written after post-GEMM1 barrier): 76KB -> 42KB LDS,
//    2 -> 3 blocks/CU.
//  - weights loaded+converted to bf16 frags before gather (f32 temps die early).

typedef __attribute__((ext_vector_type(8))) short short8;   // 8 bf16 frag
typedef __attribute__((ext_vector_type(4))) float f32x4;    // MFMA acc

constexpr int Bn  = 16;
constexpr int Mn  = 64;
constexpr int Cn  = 16;
constexpr int Hd  = 128;
constexpr int K9  = 144;
constexpr int MCn = 1024;
constexpr int NP  = 128;    // pixels per block
constexpr int PT_STRIDE = 336;  // bytes/pixel row of Pt (21 16B-slots, odd -> 2-way max)
constexpr int HT_STRIDE = 272;  // bytes/pixel row of Ht (17 slots, odd)
constexpr int NT  = 256;

__device__ __forceinline__ ushort f2bf(float f) {
    union { float f; uint u; } v; v.f = f;
    const uint u = v.u;
    return (ushort)((u + 0x7fffu + ((u >> 16) & 1u)) >> 16);   // RNE
}

__global__ __launch_bounds__(NT, 3)
void nca_mfma(const float* __restrict__ x,  const float* __restrict__ w1,
              const float* __restrict__ b1, const float* __restrict__ w2,
              const float* __restrict__ b2, float* __restrict__ out)
{
    // union: phase 0/1 = Pt[p][kp] bf16 perception (43008B);
    //        phase 2   = Ht[p][hd] bf16 hidden (34816B)
    __shared__ __align__(16) char U[NP * PT_STRIDE];
    char* const PtL = U;
    char* const HtL = U;

    const int tid  = threadIdx.x;
    const int lane = tid & 63;
    const int wid  = tid >> 6;      // wave 0..3
    const int lr   = lane & 15;     // MFMA row/col lane index
    const int lk   = lane >> 4;     // MFMA k-group 0..3

    const int m  = blockIdx.x >> 7;         // model 0..63
    const int pt = blockIdx.x & 127;        // pixel tile 0..127
    const int b  = pt >> 3;                 // batch 0..15
    const int p0 = (pt & 7) * NP;           // pixel base within image

    // ---------- w1 -> bf16 A-frags (rows wid*32..+32, 2 row-tiles x 5 ks) ----------
    short8 a1[2][5];
    #pragma unroll
    for (int rt = 0; rt < 2; ++rt) {
        const int row = wid * 32 + rt * 16 + lr;
        const float* wr = w1 + (m * Hd + row) * K9;
        #pragma unroll
        for (int ks = 0; ks < 5; ++ks) {
            const int k0 = ks * 32 + lk * 8;
            short8 t;
            if (k0 < K9) {
                const float4 f0 = *(const float4*)(wr + k0);
                const float4 f1 = *(const float4*)(wr + k0 + 4);
                t[0] = (short)f2bf(f0.x); t[1] = (short)f2bf(f0.y);
                t[2] = (short)f2bf(f0.z); t[3] = (short)f2bf(f0.w);
                t[4] = (short)f2bf(f1.x); t[5] = (short)f2bf(f1.y);
                t[6] = (short)f2bf(f1.z); t[7] = (short)f2bf(f1.w);
            } else {
                t = (short8){0,0,0,0,0,0,0,0};
            }
            a1[rt][ks] = t;
        }
    }

    // ---------- w2 -> bf16 A-frags ----------
    short8 a2[4];
    #pragma unroll
    for (int ks = 0; ks < 4; ++ks) {
        const float* wr = w2 + (m * Cn + lr) * Hd + ks * 32 + lk * 8;
        const float4 f0 = *(const float4*)(wr);
        const float4 f1 = *(const float4*)(wr + 4);
        short8 t;
        t[0] = (short)f2bf(f0.x); t[1] = (short)f2bf(f0.y);
        t[2] = (short)f2bf(f0.z); t[3] = (short)f2bf(f0.w);
        t[4] = (short)f2bf(f1.x); t[5] = (short)f2bf(f1.y);
        t[6] = (short)f2bf(f1.z); t[7] = (short)f2bf(f1.w);
        a2[ks] = t;
    }

    // ---------- gather perception -> Pt[p][kp] (packed bf16 pairs) ----------
    // 16 groups of 16 lanes; group g owns k-pairs {g, g+16, g+32, g+48, g+64}.
    // Per k-pair: channel/shift/base setup ONCE, then 8 coalesced 16-pixel chunks.
    {
        const int g  = tid >> 4;     // 0..15
        const int li = tid & 15;
        const int r0 = p0 >> 5;      // first image row of this tile

        #pragma unroll
        for (int t5 = 0; t5 < 5; ++t5) {
            const int kp = g + t5 * 16;          // 0..79
            char* const dst = PtL + kp * 4;
            if (kp < 72) {                        // real k's (k<144)
                int   chanbase[2];
                int   rbase[2];
                int   dcv[2];
                #pragma unroll
                for (int half = 0; half < 2; ++half) {
                    const int k  = kp * 2 + half;
                    const int ch = m * K9 + k;
                    const int s  = ch >> 10;
                    const int mc = ch & 1023;
                    int dr = 0, dc = 0;
                    if (s > 0) {
                        const int q  = (s - 1) < 4 ? (s - 1) : s;
                        const int q3 = q / 3;
                        dr = q3 - 1; dc = q - q3 * 3 - 1;
                    }
                    chanbase[half] = (b * MCn + mc) * 1024 + dr * 32 + dc;
                    rbase[half]    = r0 + dr;
                    dcv[half]      = dc;
                }
                #pragma unroll
                for (int c = 0; c < 8; ++c) {
                    const int p  = c * 16 + li;
                    const int gp = p0 + p;
                    const int wv = (c & 1) * 16 + li;     // w coordinate
                    uint pack = 0;
                    #pragma unroll
                    for (int half = 0; half < 2; ++half) {
                        const bool okr = (unsigned)(rbase[half] + (c >> 1)) < 32u;
                        const bool okw = (unsigned)(wv + dcv[half]) < 32u;
                        float v = 0.f;
                        if (okr & okw) v = x[chanbase[half] + gp];
                        pack |= (uint)f2bf(v) << (16 * half);
                    }
                    *(uint*)(dst + p * PT_STRIDE) = pack;
                }
            } else {                              // zero padding k in [144,160)
                #pragma unroll
                for (int c = 0; c < 8; ++c)
                    *(uint*)(dst + (c * 16 + li) * PT_STRIDE) = 0u;
            }
        }
    }
    __syncthreads();

    // ---------- GEMM1: hdn = w1 @ P, 128x128x160 ----------
    f32x4 acc[2][8];
    #pragma unroll
    for (int i = 0; i < 2; ++i)
        #pragma unroll
        for (int j = 0; j < 8; ++j) acc[i][j] = (f32x4){0.f, 0.f, 0.f, 0.f};

    #pragma unroll
    for (int ct = 0; ct < 8; ++ct) {
        const int p = ct * 16 + lr;
        const char* base = PtL + p * PT_STRIDE + lk * 16;
        short8 bfrag[5];
        #pragma unroll
        for (int ks = 0; ks < 5; ++ks)
            bfrag[ks] = *(const short8*)(base + ks * 64);
        #pragma unroll
        for (int ks = 0; ks < 5; ++ks) {
            acc[0][ct] = __builtin_amdgcn_mfma_f32_16x16x32_bf16(a1[0][ks], bfrag[ks], acc[0][ct], 0, 0, 0);
            acc[1][ct] = __builtin_amdgcn_mfma_f32_16x16x32_bf16(a1[1][ks], bfrag[ks], acc[1][ct], 0, 0, 0);
        }
    }
    __syncthreads();   // all waves done reading Pt -> safe to overwrite with Ht

    // ---------- bias+relu -> Ht[pixel][hd] bf16 (union with Pt) ----------
    #pragma unroll
    for (int rt = 0; rt < 2; ++rt) {
        const int hd0 = wid * 32 + rt * 16 + lk * 4;   // C/D row = (lane>>4)*4 + reg
        const float4 bs = *(const float4*)(b1 + m * Hd + hd0);
        #pragma unroll
        for (int ct = 0; ct < 8; ++ct) {
            const int p = ct * 16 + lr;                // C/D col = lane&15
            const f32x4 v = acc[rt][ct];
            const uint lo = (uint)f2bf(fmaxf(v[0] + bs.x, 0.f)) |
                            ((uint)f2bf(fmaxf(v[1] + bs.y, 0.f)) << 16);
            const uint hi = (uint)f2bf(fmaxf(v[2] + bs.z, 0.f)) |
                            ((uint)f2bf(fmaxf(v[3] + bs.w, 0.f)) << 16);
            uint2 pk; pk.x = lo; pk.y = hi;
            *(uint2*)(HtL + p * HT_STRIDE + hd0 * 2) = pk;
        }
    }
    __syncthreads();

    // ---------- GEMM2: dx = w2 @ hdn, 16x128x128 ----------
    f32x4 acc2[2];
    #pragma unroll
    for (int j = 0; j < 2; ++j) {
        const int ct = wid * 2 + j;           // 4 waves x 2 = 8 col-tiles
        const int p  = ct * 16 + lr;
        const char* base = HtL + p * HT_STRIDE + lk * 16;
        short8 bb[4];
        #pragma unroll
        for (int ks = 0; ks < 4; ++ks)
            bb[ks] = *(const short8*)(base + ks * 64);
        f32x4 a = (f32x4){0.f, 0.f, 0.f, 0.f};
        #pragma unroll
        for (int ks = 0; ks < 4; ++ks)
            a = __builtin_amdgcn_mfma_f32_16x16x32_bf16(a2[ks], bb[ks], a, 0, 0, 0);
        acc2[j] = a;
    }

    // ---------- epilogue: out = x + dx + b2 ----------
    const float4 b2v = *(const float4*)(b2 + m * Cn + lk * 4);
    const float bsv[4] = {b2v.x, b2v.y, b2v.z, b2v.w};
    #pragma unroll
    for (int j = 0; j < 2; ++j) {
        const int ct = wid * 2 + j;
        const int gp = p0 + ct * 16 + lr;
        #pragma unroll
        for (int r = 0; r < 4; ++r) {
            const int c   = lk * 4 + r;
            const int idx = (b * MCn + m * Cn + c) * 1024 + gp;
            out[idx] = x[idx] + acc2[j][r] + bsv[r];
        }
    }
}

extern "C" void kernel_launch(void* const* d_in, const int* in_sizes, int n_in,
                              void* d_out, int out_size, void* d_ws, size_t ws_size,
                              hipStream_t stream)
{
    const float* x  = (const float*)d_in[0];
    const float* w1 = (const float*)d_in[1];
    const float* b1 = (const float*)d_in[2];
    const float* w2 = (const float*)d_in[3];
    const float* b2 = (const float*)d_in[4];
    float* out = (float*)d_out;

    const int grid = Mn * (Bn * 1024 / NP);   // 64 * 128 = 8192
    nca_mfma<<<grid, NT, 0, stream>>>(x, w1, b1, w2, b2, out);
}

// Round 5
// 244.427 us; speedup vs baseline: 4.8335x; 1.0998x over previous
//
#include <hip/hip_runtime.h>

// ParallelNCA on MFMA: 64 grouped MLPs (144->128->16) over 3x3 perception.
// Per block: (m, 128-pixel tile). GEMM1 128x128x160(bf16), GEMM2 16x128x128.
// Round 4 change vs round 3:
//  - XCD-group blockIdx swizzle: all 64 m-blocks of one (b,tile) group land on
//    the SAME XCD as a contiguous dispatch run. Their x-reads union to 786KB
//    (fits 4MB XCD L2); each element is read 9x across the group -> L2 hits
//    instead of HBM misses. blockIdx%8 = XCD (round-robin dispatch, m09).

typedef __attribute__((ext_vector_type(8))) short short8;   // 8 bf16 frag
typedef __attribute__((ext_vector_type(4))) float f32x4;    // MFMA acc

constexpr int Bn  = 16;
constexpr int Mn  = 64;
constexpr int Cn  = 16;
constexpr int Hd  = 128;
constexpr int K9  = 144;
constexpr int MCn = 1024;
constexpr int NP  = 128;    // pixels per block
constexpr int PT_STRIDE = 336;  // bytes/pixel row of Pt (21 16B-slots, odd -> 2-way max)
constexpr int HT_STRIDE = 272;  // bytes/pixel row of Ht (17 slots, odd)
constexpr int NT  = 256;

__device__ __forceinline__ ushort f2bf(float f) {
    union { float f; uint u; } v; v.f = f;
    const uint u = v.u;
    return (ushort)((u + 0x7fffu + ((u >> 16) & 1u)) >> 16);   // RNE
}

__global__ __launch_bounds__(NT, 3)
void nca_mfma(const float* __restrict__ x,  const float* __restrict__ w1,
              const float* __restrict__ b1, const float* __restrict__ w2,
              const float* __restrict__ b2, float* __restrict__ out)
{
    // union: phase 0/1 = Pt[p][kp] bf16 perception (43008B);
    //        phase 2   = Ht[p][hd] bf16 hidden (34816B)
    __shared__ __align__(16) char U[NP * PT_STRIDE];
    char* const PtL = U;
    char* const HtL = U;

    const int tid  = threadIdx.x;
    const int lane = tid & 63;
    const int wid  = tid >> 6;      // wave 0..3
    const int lr   = lane & 15;     // MFMA row/col lane index
    const int lk   = lane >> 4;     // MFMA k-group 0..3

    // XCD-group swizzle: xcd = bid&7 (round-robin dispatch); consecutive j at
    // fixed xcd sweep m=0..63 within one (b,tile) group g = (j>>6)*8 + xcd.
    const int bid = blockIdx.x;
    const int xcd = bid & 7;
    const int j   = bid >> 3;
    const int m   = j & 63;                 // model 0..63
    const int g   = (j >> 6) * 8 + xcd;     // pixel group 0..127
    const int b   = g >> 3;                 // batch 0..15
    const int p0  = (g & 7) * NP;           // pixel base within image

    // ---------- w1 -> bf16 A-frags (rows wid*32..+32, 2 row-tiles x 5 ks) ----------
    short8 a1[2][5];
    #pragma unroll
    for (int rt = 0; rt < 2; ++rt) {
        const int row = wid * 32 + rt * 16 + lr;
        const float* wr = w1 + (m * Hd + row) * K9;
        #pragma unroll
        for (int ks = 0; ks < 5; ++ks) {
            const int k0 = ks * 32 + lk * 8;
            short8 t;
            if (k0 < K9) {
                const float4 f0 = *(const float4*)(wr + k0);
                const float4 f1 = *(const float4*)(wr + k0 + 4);
                t[0] = (short)f2bf(f0.x); t[1] = (short)f2bf(f0.y);
                t[2] = (short)f2bf(f0.z); t[3] = (short)f2bf(f0.w);
                t[4] = (short)f2bf(f1.x); t[5] = (short)f2bf(f1.y);
                t[6] = (short)f2bf(f1.z); t[7] = (short)f2bf(f1.w);
            } else {
                t = (short8){0,0,0,0,0,0,0,0};
            }
            a1[rt][ks] = t;
        }
    }

    // ---------- w2 -> bf16 A-frags ----------
    short8 a2[4];
    #pragma unroll
    for (int ks = 0; ks < 4; ++ks) {
        const float* wr = w2 + (m * Cn + lr) * Hd + ks * 32 + lk * 8;
        const float4 f0 = *(const float4*)(wr);
        const float4 f1 = *(const float4*)(wr + 4);
        short8 t;
        t[0] = (short)f2bf(f0.x); t[1] = (short)f2bf(f0.y);
        t[2] = (short)f2bf(f0.z); t[3] = (short)f2bf(f0.w);
        t[4] = (short)f2bf(f1.x); t[5] = (short)f2bf(f1.y);
        t[6] = (short)f2bf(f1.z); t[7] = (short)f2bf(f1.w);
        a2[ks] = t;
    }

    // ---------- gather perception -> Pt[p][kp] (packed bf16 pairs) ----------
    // 16 groups of 16 lanes; group gq owns k-pairs {gq, gq+16, gq+32, gq+48, gq+64}.
    // Per k-pair: channel/shift/base setup ONCE, then 8 coalesced 16-pixel chunks.
    {
        const int gq = tid >> 4;     // 0..15
        const int li = tid & 15;
        const int r0 = p0 >> 5;      // first image row of this tile

        #pragma unroll
        for (int t5 = 0; t5 < 5; ++t5) {
            const int kp = gq + t5 * 16;          // 0..79
            char* const dst = PtL + kp * 4;
            if (kp < 72) {                        // real k's (k<144)
                int   chanbase[2];
                int   rbase[2];
                int   dcv[2];
                #pragma unroll
                for (int half = 0; half < 2; ++half) {
                    const int k  = kp * 2 + half;
                    const int ch = m * K9 + k;
                    const int s  = ch >> 10;
                    const int mc = ch & 1023;
                    int dr = 0, dc = 0;
                    if (s > 0) {
                        const int q  = (s - 1) < 4 ? (s - 1) : s;
                        const int q3 = q / 3;
                        dr = q3 - 1; dc = q - q3 * 3 - 1;
                    }
                    chanbase[half] = (b * MCn + mc) * 1024 + dr * 32 + dc;
                    rbase[half]    = r0 + dr;
                    dcv[half]      = dc;
                }
                #pragma unroll
                for (int c = 0; c < 8; ++c) {
                    const int p  = c * 16 + li;
                    const int gp = p0 + p;
                    const int wv = (c & 1) * 16 + li;     // w coordinate
                    uint pack = 0;
                    #pragma unroll
                    for (int half = 0; half < 2; ++half) {
                        const bool okr = (unsigned)(rbase[half] + (c >> 1)) < 32u;
                        const bool okw = (unsigned)(wv + dcv[half]) < 32u;
                        float v = 0.f;
                        if (okr & okw) v = x[chanbase[half] + gp];
                        pack |= (uint)f2bf(v) << (16 * half);
                    }
                    *(uint*)(dst + p * PT_STRIDE) = pack;
                }
            } else {                              // zero padding k in [144,160)
                #pragma unroll
                for (int c = 0; c < 8; ++c)
                    *(uint*)(dst + (c * 16 + li) * PT_STRIDE) = 0u;
            }
        }
    }
    __syncthreads();

    // ---------- GEMM1: hdn = w1 @ P, 128x128x160 ----------
    f32x4 acc[2][8];
    #pragma unroll
    for (int i = 0; i < 2; ++i)
        #pragma unroll
        for (int jj = 0; jj < 8; ++jj) acc[i][jj] = (f32x4){0.f, 0.f, 0.f, 0.f};

    #pragma unroll
    for (int ct = 0; ct < 8; ++ct) {
        const int p = ct * 16 + lr;
        const char* base = PtL + p * PT_STRIDE + lk * 16;
        short8 bfrag[5];
        #pragma unroll
        for (int ks = 0; ks < 5; ++ks)
            bfrag[ks] = *(const short8*)(base + ks * 64);
        #pragma unroll
        for (int ks = 0; ks < 5; ++ks) {
            acc[0][ct] = __builtin_amdgcn_mfma_f32_16x16x32_bf16(a1[0][ks], bfrag[ks], acc[0][ct], 0, 0, 0);
            acc[1][ct] = __builtin_amdgcn_mfma_f32_16x16x32_bf16(a1[1][ks], bfrag[ks], acc[1][ct], 0, 0, 0);
        }
    }
    __syncthreads();   // all waves done reading Pt -> safe to overwrite with Ht

    // ---------- bias+relu -> Ht[pixel][hd] bf16 (union with Pt) ----------
    #pragma unroll
    for (int rt = 0; rt < 2; ++rt) {
        const int hd0 = wid * 32 + rt * 16 + lk * 4;   // C/D row = (lane>>4)*4 + reg
        const float4 bs = *(const float4*)(b1 + m * Hd + hd0);
        #pragma unroll
        for (int ct = 0; ct < 8; ++ct) {
            const int p = ct * 16 + lr;                // C/D col = lane&15
            const f32x4 v = acc[rt][ct];
            const uint lo = (uint)f2bf(fmaxf(v[0] + bs.x, 0.f)) |
                            ((uint)f2bf(fmaxf(v[1] + bs.y, 0.f)) << 16);
            const uint hi = (uint)f2bf(fmaxf(v[2] + bs.z, 0.f)) |
                            ((uint)f2bf(fmaxf(v[3] + bs.w, 0.f)) << 16);
            uint2 pk; pk.x = lo; pk.y = hi;
            *(uint2*)(HtL + p * HT_STRIDE + hd0 * 2) = pk;
        }
    }
    __syncthreads();

    // ---------- GEMM2: dx = w2 @ hdn, 16x128x128 ----------
    f32x4 acc2[2];
    #pragma unroll
    for (int jj = 0; jj < 2; ++jj) {
        const int ct = wid * 2 + jj;          // 4 waves x 2 = 8 col-tiles
        const int p  = ct * 16 + lr;
        const char* base = HtL + p * HT_STRIDE + lk * 16;
        short8 bb[4];
        #pragma unroll
        for (int ks = 0; ks < 4; ++ks)
            bb[ks] = *(const short8*)(base + ks * 64);
        f32x4 a = (f32x4){0.f, 0.f, 0.f, 0.f};
        #pragma unroll
        for (int ks = 0; ks < 4; ++ks)
            a = __builtin_amdgcn_mfma_f32_16x16x32_bf16(a2[ks], bb[ks], a, 0, 0, 0);
        acc2[jj] = a;
    }

    // ---------- epilogue: out = x + dx + b2 ----------
    const float4 b2v = *(const float4*)(b2 + m * Cn + lk * 4);
    const float bsv[4] = {b2v.x, b2v.y, b2v.z, b2v.w};
    #pragma unroll
    for (int jj = 0; jj < 2; ++jj) {
        const int ct = wid * 2 + jj;
        const int gp = p0 + ct * 16 + lr;
        #pragma unroll
        for (int r = 0; r < 4; ++r) {
            const int c   = lk * 4 + r;
            const int idx = (b * MCn + m * Cn + c) * 1024 + gp;
            out[idx] = x[idx] + acc2[jj][r] + bsv[r];
        }
    }
}

extern "C" void kernel_launch(void* const* d_in, const int* in_sizes, int n_in,
                              void* d_out, int out_size, void* d_ws, size_t ws_size,
                              hipStream_t stream)
{
    const float* x  = (const float*)d_in[0];
    const float* w1 = (const float*)d_in[1];
    const float* b1 = (const float*)d_in[2];
    const float* w2 = (const float*)d_in[3];
    const float* b2 = (const float*)d_in[4];
    float* out = (float*)d_out;

    const int grid = Mn * (Bn * 1024 / NP);   // 64 * 128 = 8192
    nca_mfma<<<grid, NT, 0, stream>>>(x, w1, b1, w2, b2, out);
}

// Round 6
// 195.261 us; speedup vs baseline: 6.0505x; 1.2518x over previous
//
#include <hip/hip_runtime.h>
#include <hip/hip_bf16.h>

// ParallelNCA on MFMA: 64 grouped MLPs (144->128->16) over 3x3 perception.
// Per block: (m, 128-pixel tile). GEMM1 128x128x160(bf16), GEMM2 16x128x128.
// Round 5 changes vs round 4:
//  - PT_STRIDE 336->304B (288B data + 16B zero pad): LDS 42->38.9KB -> 4 blocks/CU.
//  - gather re-vectorized: each lane loads float4 strips (18 loads/thread vs 80),
//    8 lanes cover one full 128B image row; edge handling via clamp+shift-select;
//    (dr,dc) decode via packed nibble table; bf16 cvt via __float2bfloat16.

typedef __attribute__((ext_vector_type(8))) short short8;   // 8 bf16 frag
typedef __attribute__((ext_vector_type(4))) float f32x4;    // MFMA acc

constexpr int Bn  = 16;
constexpr int Mn  = 64;
constexpr int Cn  = 16;
constexpr int Hd  = 128;
constexpr int K9  = 144;
constexpr int MCn = 1024;
constexpr int NP  = 128;        // pixels per block (4 image rows)
constexpr int PT_STRIDE = 304;  // bytes/pixel row of Pt: 152 bf16 slots (144 data + 8 pad)
constexpr int HT_STRIDE = 272;  // bytes/pixel row of Ht (17 16B-slots, odd)
constexpr int NT  = 256;

__device__ __forceinline__ ushort f2bf(float f) {
    return __bfloat16_as_ushort(__float2bfloat16(f));
}

__global__ __launch_bounds__(NT, 4)
void nca_mfma(const float* __restrict__ x,  const float* __restrict__ w1,
              const float* __restrict__ b1, const float* __restrict__ w2,
              const float* __restrict__ b2, float* __restrict__ out)
{
    // union: phase 0/1 = Pt[p][kp] bf16 perception; phase 2 = Ht[p][hd] bf16 hidden.
    // +16B guard so the ks=4/lk=3 b128 read at p=127 stays in-bounds (zeroed).
    __shared__ __align__(16) char U[NP * PT_STRIDE + 16];
    char* const PtL = U;
    char* const HtL = U;

    const int tid  = threadIdx.x;
    const int lane = tid & 63;
    const int wid  = tid >> 6;      // wave 0..3
    const int lr   = lane & 15;     // MFMA row/col lane index
    const int lk   = lane >> 4;     // MFMA k-group 0..3

    // XCD-group swizzle (kept from round 4: -25us vs unswizzled).
    const int bid = blockIdx.x;
    const int xcd = bid & 7;
    const int j   = bid >> 3;
    const int m   = j & 63;                 // model 0..63
    const int g   = (j >> 6) * 8 + xcd;     // pixel group 0..127
    const int b   = g >> 3;                 // batch 0..15
    const int p0  = (g & 7) * NP;           // pixel base within image

    // ---------- zero-fill k-pad (bytes 288..304 of each row) + guard row ----------
    if (tid <= NP) {
        char* z = PtL + tid * PT_STRIDE + (tid < NP ? 288 : 0);
        *(int4*)z = (int4){0, 0, 0, 0};
    }

    // ---------- w1 -> bf16 A-frags (rows wid*32..+32, 2 row-tiles x 5 ks) ----------
    short8 a1[2][5];
    #pragma unroll
    for (int rt = 0; rt < 2; ++rt) {
        const int row = wid * 32 + rt * 16 + lr;
        const float* wr = w1 + (m * Hd + row) * K9;
        #pragma unroll
        for (int ks = 0; ks < 5; ++ks) {
            const int k0 = ks * 32 + lk * 8;
            short8 t;
            if (k0 < K9) {
                const float4 f0 = *(const float4*)(wr + k0);
                const float4 f1 = *(const float4*)(wr + k0 + 4);
                t[0] = (short)f2bf(f0.x); t[1] = (short)f2bf(f0.y);
                t[2] = (short)f2bf(f0.z); t[3] = (short)f2bf(f0.w);
                t[4] = (short)f2bf(f1.x); t[5] = (short)f2bf(f1.y);
                t[6] = (short)f2bf(f1.z); t[7] = (short)f2bf(f1.w);
            } else {
                t = (short8){0,0,0,0,0,0,0,0};
            }
            a1[rt][ks] = t;
        }
    }

    // ---------- w2 -> bf16 A-frags ----------
    short8 a2[4];
    #pragma unroll
    for (int ks = 0; ks < 4; ++ks) {
        const float* wr = w2 + (m * Cn + lr) * Hd + ks * 32 + lk * 8;
        const float4 f0 = *(const float4*)(wr);
        const float4 f1 = *(const float4*)(wr + 4);
        short8 t;
        t[0] = (short)f2bf(f0.x); t[1] = (short)f2bf(f0.y);
        t[2] = (short)f2bf(f0.z); t[3] = (short)f2bf(f0.w);
        t[4] = (short)f2bf(f1.x); t[5] = (short)f2bf(f1.y);
        t[6] = (short)f2bf(f1.z); t[7] = (short)f2bf(f1.w);
        a2[ks] = t;
    }

    // ---------- gather perception -> Pt[p][kp] (packed bf16 pairs) ----------
    // Thread owns (strip s, k-pair column kpl, image row r=wave). 9 iterations,
    // each: 2 float4 loads (channels 2kp, 2kp+1 at 4 consecutive pixels),
    // cvt+pack, 4 ds_write_b32. 8 lanes = one contiguous 128B image row.
    {
        const int s     = tid & 7;          // 4-pixel strip within row
        const int kpl   = (tid >> 3) & 7;   // k-pair low index
        const int r     = tid >> 6;         // row within tile (== wave)
        const int rbase = (g & 7) * 4 + r;  // image row
        const float* xb = x + b * (MCn * 1024);
        // (dr+1)|((dc+1)<<2) nibbles for shifts s=0..8
        const unsigned long long TAB = 0xA62918405ull;

        #pragma unroll
        for (int it = 0; it < 9; ++it) {
            const int kp = it * 8 + kpl;    // 0..71 (all real: 72*2=144=K9)
            float4 hv[2];
            #pragma unroll
            for (int half = 0; half < 2; ++half) {
                const int ch = m * K9 + kp * 2 + half;
                const int sh = ch >> 10;
                const int mc = ch & 1023;
                const uint nib = (uint)(TAB >> (4 * sh)) & 15u;
                const int dr = (int)(nib & 3u) - 1;
                const int dc = (int)(nib >> 2) - 1;
                const int row = rbase + dr;
                const int wb  = 4 * s + dc;
                const int wc  = min(max(wb, 0), 28);
                float4 f = {0.f, 0.f, 0.f, 0.f};
                if ((unsigned)row < 32u)
                    f = *(const float4*)(xb + (mc * 32 + row) * 32 + wc);
                if (wb < 0)       { f.w = f.z; f.z = f.y; f.y = f.x; f.x = 0.f; }
                else if (wb > 28) { f.x = f.y; f.y = f.z; f.z = f.w; f.w = 0.f; }
                hv[half] = f;
            }
            char* dst = PtL + (r * 32 + 4 * s) * PT_STRIDE + kp * 4;
            *(uint*)(dst)                 = (uint)f2bf(hv[0].x) | ((uint)f2bf(hv[1].x) << 16);
            *(uint*)(dst + PT_STRIDE)     = (uint)f2bf(hv[0].y) | ((uint)f2bf(hv[1].y) << 16);
            *(uint*)(dst + 2 * PT_STRIDE) = (uint)f2bf(hv[0].z) | ((uint)f2bf(hv[1].z) << 16);
            *(uint*)(dst + 3 * PT_STRIDE) = (uint)f2bf(hv[0].w) | ((uint)f2bf(hv[1].w) << 16);
        }
    }
    __syncthreads();

    // ---------- GEMM1: hdn = w1 @ P, 128x128x160 ----------
    f32x4 acc[2][8];
    #pragma unroll
    for (int i = 0; i < 2; ++i)
        #pragma unroll
        for (int jj = 0; jj < 8; ++jj) acc[i][jj] = (f32x4){0.f, 0.f, 0.f, 0.f};

    #pragma unroll
    for (int ct = 0; ct < 8; ++ct) {
        const int p = ct * 16 + lr;
        const char* base = PtL + p * PT_STRIDE + lk * 16;
        short8 bfrag[5];
        #pragma unroll
        for (int ks = 0; ks < 5; ++ks)
            bfrag[ks] = *(const short8*)(base + ks * 64);
        #pragma unroll
        for (int ks = 0; ks < 5; ++ks) {
            acc[0][ct] = __builtin_amdgcn_mfma_f32_16x16x32_bf16(a1[0][ks], bfrag[ks], acc[0][ct], 0, 0, 0);
            acc[1][ct] = __builtin_amdgcn_mfma_f32_16x16x32_bf16(a1[1][ks], bfrag[ks], acc[1][ct], 0, 0, 0);
        }
    }
    __syncthreads();   // all waves done reading Pt -> safe to overwrite with Ht

    // ---------- bias+relu -> Ht[pixel][hd] bf16 (union with Pt) ----------
    #pragma unroll
    for (int rt = 0; rt < 2; ++rt) {
        const int hd0 = wid * 32 + rt * 16 + lk * 4;   // C/D row = (lane>>4)*4 + reg
        const float4 bs = *(const float4*)(b1 + m * Hd + hd0);
        #pragma unroll
        for (int ct = 0; ct < 8; ++ct) {
            const int p = ct * 16 + lr;                // C/D col = lane&15
            const f32x4 v = acc[rt][ct];
            const uint lo = (uint)f2bf(fmaxf(v[0] + bs.x, 0.f)) |
                            ((uint)f2bf(fmaxf(v[1] + bs.y, 0.f)) << 16);
            const uint hi = (uint)f2bf(fmaxf(v[2] + bs.z, 0.f)) |
                            ((uint)f2bf(fmaxf(v[3] + bs.w, 0.f)) << 16);
            uint2 pk; pk.x = lo; pk.y = hi;
            *(uint2*)(HtL + p * HT_STRIDE + hd0 * 2) = pk;
        }
    }
    __syncthreads();

    // ---------- GEMM2: dx = w2 @ hdn, 16x128x128 ----------
    f32x4 acc2[2];
    #pragma unroll
    for (int jj = 0; jj < 2; ++jj) {
        const int ct = wid * 2 + jj;          // 4 waves x 2 = 8 col-tiles
        const int p  = ct * 16 + lr;
        const char* base = HtL + p * HT_STRIDE + lk * 16;
        short8 bb[4];
        #pragma unroll
        for (int ks = 0; ks < 4; ++ks)
            bb[ks] = *(const short8*)(base + ks * 64);
        f32x4 a = (f32x4){0.f, 0.f, 0.f, 0.f};
        #pragma unroll
        for (int ks = 0; ks < 4; ++ks)
            a = __builtin_amdgcn_mfma_f32_16x16x32_bf16(a2[ks], bb[ks], a, 0, 0, 0);
        acc2[jj] = a;
    }

    // ---------- epilogue: out = x + dx + b2 ----------
    const float4 b2v = *(const float4*)(b2 + m * Cn + lk * 4);
    const float bsv[4] = {b2v.x, b2v.y, b2v.z, b2v.w};
    #pragma unroll
    for (int jj = 0; jj < 2; ++jj) {
        const int ct = wid * 2 + jj;
        const int gp = p0 + ct * 16 + lr;
        #pragma unroll
        for (int r = 0; r < 4; ++r) {
            const int c   = lk * 4 + r;
            const int idx = (b * MCn + m * Cn + c) * 1024 + gp;
            out[idx] = x[idx] + acc2[jj][r] + bsv[r];
        }
    }
}

extern "C" void kernel_launch(void* const* d_in, const int* in_sizes, int n_in,
                              void* d_out, int out_size, void* d_ws, size_t ws_size,
                              hipStream_t stream)
{
    const float* x  = (const float*)d_in[0];
    const float* w1 = (const float*)d_in[1];
    const float* b1 = (const float*)d_in[2];
    const float* w2 = (const float*)d_in[3];
    const float* b2 = (const float*)d_in[4];
    float* out = (float*)d_out;

    const int grid = Mn * (Bn * 1024 / NP);   // 64 * 128 = 8192
    nca_mfma<<<grid, NT, 0, stream>>>(x, w1, b1, w2, b2, out);
}

// Round 7
// 142.163 us; speedup vs baseline: 8.3104x; 1.3735x over previous
//
#include <hip/hip_runtime.h>
#include <hip/hip_bf16.h>

// ParallelNCA on MFMA: 64 grouped MLPs (144->128->16) over 3x3 perception.
// Round 7: bf16-precomputed x (padded, zero-bordered) in d_ws; aligned uint4
// gather with alignbit/perm shifts; rotated LDS writes (2-way banks);
// epilogue LDS transpose for 512B-contiguous out writes. Fallback = round 6.

typedef __attribute__((ext_vector_type(8))) short short8;   // 8 bf16 frag
typedef __attribute__((ext_vector_type(4))) float f32x4;    // MFMA acc

constexpr int Bn  = 16;
constexpr int Mn  = 64;
constexpr int Cn  = 16;
constexpr int Hd  = 128;
constexpr int K9  = 144;
constexpr int MCn = 1024;
constexpr int NP  = 128;        // pixels per block (4 image rows)
constexpr int PT_STRIDE = 304;  // bytes/pixel row of Pt (76 words; 16B-mult)
constexpr int HT_STRIDE = 272;  // bytes/pixel row of Ht
constexpr int NT  = 256;

// padded bf16 x: [b][mc][34 rows][40 ushorts] ; row h stored at h+1, col w at w+4
constexpr int XROW = 80;            // bytes per padded row
constexpr int XCH  = 34 * XROW;     // 2720 B per channel
constexpr size_t XBF_BYTES = (size_t)Bn * MCn * XCH;            // 44,564,480
constexpr size_t W1_ELEMS  = (size_t)Mn * Hd * K9;              // 1,179,648
constexpr size_t W2_ELEMS  = (size_t)Mn * Cn * Hd;              // 131,072
constexpr size_t WS_NEED   = XBF_BYTES + 2 * (W1_ELEMS + W2_ELEMS);

__device__ __forceinline__ ushort f2bf(float f) {
    return __bfloat16_as_ushort(__float2bfloat16(f));
}

// ---------------------------------------------------------------------------
// prep: x (f32 [b][mc][32][32]) -> xbf (bf16 padded [b*mc][34][40], zero borders)
// ---------------------------------------------------------------------------
__global__ __launch_bounds__(256)
void prep_x(const float* __restrict__ x, ushort* __restrict__ xbf)
{
    const int blk = blockIdx.x;          // b*1024 + mc
    const int tid = threadIdx.x;
    char* chbase = (char*)xbf + (size_t)blk * XCH;

    // borders (disjoint from interior writes -> no barrier needed)
    if (tid < 168) {
        if (tid < 40) {
            const int r = (tid < 20) ? 0 : 33;
            const int jq = tid % 20;
            *(uint*)(chbase + r * XROW + 4 * jq) = 0u;
        } else {
            const int e = tid - 40;
            const int r = 1 + (e >> 2);
            const int jq = (e & 2) ? (18 + (e & 1)) : (e & 1);
            *(uint*)(chbase + r * XROW + 4 * jq) = 0u;
        }
    }
    // interior: thread -> (h = tid>>3, 4-px quad q = tid&7)
    const int h = tid >> 3, q = tid & 7;
    const float4 f = *(const float4*)(x + ((size_t)blk * 32 + h) * 32 + 4 * q);
    uint2 pk;
    pk.x = (uint)f2bf(f.x) | ((uint)f2bf(f.y) << 16);
    pk.y = (uint)f2bf(f.z) | ((uint)f2bf(f.w) << 16);
    *(uint2*)(chbase + (h + 1) * XROW + 8 * q + 8) = pk;   // 8-aligned
}

// ---------------------------------------------------------------------------
// prep: weights f32 -> bf16 (same layouts)
// ---------------------------------------------------------------------------
__global__ __launch_bounds__(256)
void prep_w(const float* __restrict__ w1, const float* __restrict__ w2,
            ushort* __restrict__ w1bf, ushort* __restrict__ w2bf)
{
    const size_t i = ((size_t)blockIdx.x * 256 + threadIdx.x) * 4;
    const float* src; ushort* dst; size_t e;
    if (i < W1_ELEMS) { src = w1; dst = w1bf; e = i; }
    else              { src = w2; dst = w2bf; e = i - W1_ELEMS; }
    const float4 f = *(const float4*)(src + e);
    uint2 pk;
    pk.x = (uint)f2bf(f.x) | ((uint)f2bf(f.y) << 16);
    pk.y = (uint)f2bf(f.z) | ((uint)f2bf(f.w) << 16);
    *(uint2*)(dst + e) = pk;
}

// ---------------------------------------------------------------------------
// main kernel (bf16 source)
// ---------------------------------------------------------------------------
__global__ __launch_bounds__(NT, 4)
void nca_mfma_bf16(const float* __restrict__ x, const ushort* __restrict__ xbf,
                   const ushort* __restrict__ w1bf, const float* __restrict__ b1,
                   const ushort* __restrict__ w2bf, const float* __restrict__ b2,
                   float* __restrict__ out)
{
    // union: Pt[p][kp] bf16 perception; then Ht[p][hd] bf16 hidden; then dxT f32.
    __shared__ __align__(16) char U[NP * PT_STRIDE + 16];
    char* const PtL = U;
    char* const HtL = U;

    const int tid  = threadIdx.x;
    const int lane = tid & 63;
    const int wid  = tid >> 6;      // wave 0..3
    const int lr   = lane & 15;     // MFMA row/col lane index
    const int lk   = lane >> 4;     // MFMA k-group 0..3

    // XCD-group swizzle (round 4: kept, faster)
    const int bid = blockIdx.x;
    const int xcd = bid & 7;
    const int jb  = bid >> 3;
    const int m   = jb & 63;                // model 0..63
    const int g   = (jb >> 6) * 8 + xcd;    // pixel group 0..127
    const int b   = g >> 3;                 // batch 0..15
    const int p0  = (g & 7) * NP;           // pixel base within image

    // zero k-pad columns (NaN guard for MFMA's 0*garbage) + guard row
    if (tid <= NP) {
        char* z = PtL + tid * PT_STRIDE + (tid < NP ? 288 : 0);
        *(int4*)z = (int4){0, 0, 0, 0};
    }

    // ---------- w1 bf16 A-frags ----------
    short8 a1[2][5];
    #pragma unroll
    for (int rt = 0; rt < 2; ++rt) {
        const int row = wid * 32 + rt * 16 + lr;
        const ushort* wr = w1bf + (m * Hd + row) * K9;
        #pragma unroll
        for (int ks = 0; ks < 5; ++ks) {
            const int k0 = ks * 32 + lk * 8;
            a1[rt][ks] = (k0 < K9) ? *(const short8*)(wr + k0)
                                   : (short8){0,0,0,0,0,0,0,0};
        }
    }
    // ---------- w2 bf16 A-frags ----------
    short8 a2[4];
    #pragma unroll
    for (int ks = 0; ks < 4; ++ks)
        a2[ks] = *(const short8*)(w2bf + (m * Cn + lr) * Hd + ks * 32 + lk * 8);

    // ---------- gather: xbf -> Pt[p][kp] (packed bf16 channel-pairs) ----------
    // thread = (s2 = 8-px strip 0..3, kpl 0..15, r = row 0..3). 5 iters
    // (last half-active). Loads: 2x uint4 per channel, 16B-aligned.
    {
        const int s2  = tid & 3;
        const int kpl = (tid >> 2) & 15;
        const int r   = tid >> 6;
        const int rbase = (g & 7) * 4 + r;
        const char* xbc = (const char*)xbf + (size_t)b * (MCn * XCH);
        const unsigned long long TAB = 0xA62918405ull;  // (dr+1)|((dc+1)<<2) per shift
        char* const dstrow = PtL + (r * 32 + 8 * s2) * PT_STRIDE;
        const int s2B = s2 * PT_STRIDE;

        #pragma unroll
        for (int it = 0; it < 5; ++it) {
            const int kp = it * 16 + kpl;        // 0..79; active < 72
            if (kp < 72) {
                uint rr[2][4];
                #pragma unroll
                for (int half = 0; half < 2; ++half) {
                    const int ch = m * K9 + kp * 2 + half;
                    const int sh = ch >> 10;
                    const int mc = ch & 1023;
                    const uint nib = (uint)(TAB >> (4 * sh)) & 15u;
                    const int dr = (int)(nib & 3u) - 1;
                    const int dc = (int)(nib >> 2) - 1;
                    const char* rp = xbc + (mc * 34 + rbase + dr + 1) * XROW + 16 * s2;
                    const uint4 va = *(const uint4*)(rp);
                    const uint4 vb = *(const uint4*)(rp + 16);
                    // extract ushorts [o, o+8), o = 4+dc in {3,4,5}
                    const int o  = 4 + dc;
                    const uint shb = (uint)((o & 1) << 4);
                    const bool hiq = (o >> 1) == 2;
                    const uint e0 = hiq ? va.z : va.y;
                    const uint e1 = hiq ? va.w : va.z;
                    const uint e2 = hiq ? vb.x : va.w;
                    const uint e3 = hiq ? vb.y : vb.x;
                    const uint e4 = hiq ? vb.z : vb.y;
                    rr[half][0] = __builtin_amdgcn_alignbit(e1, e0, shb);
                    rr[half][1] = __builtin_amdgcn_alignbit(e2, e1, shb);
                    rr[half][2] = __builtin_amdgcn_alignbit(e3, e2, shb);
                    rr[half][3] = __builtin_amdgcn_alignbit(e4, e3, shb);
                }
                // interleave: out_px pairs (ch0|ch1<<16)
                uint o0 = __builtin_amdgcn_perm(rr[1][0], rr[0][0], 0x05040100u);
                uint o1 = __builtin_amdgcn_perm(rr[1][0], rr[0][0], 0x07060302u);
                uint o2 = __builtin_amdgcn_perm(rr[1][1], rr[0][1], 0x05040100u);
                uint o3 = __builtin_amdgcn_perm(rr[1][1], rr[0][1], 0x07060302u);
                uint o4 = __builtin_amdgcn_perm(rr[1][2], rr[0][2], 0x05040100u);
                uint o5 = __builtin_amdgcn_perm(rr[1][2], rr[0][2], 0x07060302u);
                uint o6 = __builtin_amdgcn_perm(rr[1][3], rr[0][3], 0x05040100u);
                uint o7 = __builtin_amdgcn_perm(rr[1][3], rr[0][3], 0x07060302u);
                // rotate tuple left by s2 (banks: 76*drow mod 32 spreads lanes)
                const bool c1 = s2 & 1, c2 = s2 & 2;
                uint n0 = c1 ? o1 : o0, n1 = c1 ? o2 : o1, n2 = c1 ? o3 : o2,
                     n3 = c1 ? o4 : o3, n4 = c1 ? o5 : o4, n5 = c1 ? o6 : o5,
                     n6 = c1 ? o7 : o6, n7 = c1 ? o0 : o7;
                uint t0 = c2 ? n2 : n0, t1 = c2 ? n3 : n1, t2 = c2 ? n4 : n2,
                     t3 = c2 ? n5 : n3, t4 = c2 ? n6 : n4, t5 = c2 ? n7 : n5,
                     t6 = c2 ? n0 : n6, t7 = c2 ? n1 : n7;
                char* const dstb = dstrow + kp * 4;
                #pragma unroll
                for (int j2 = 0; j2 < 8; ++j2) {
                    int off = s2B + j2 * PT_STRIDE;
                    if (off >= 8 * PT_STRIDE) off -= 8 * PT_STRIDE;
                    const uint val = (j2 == 0) ? t0 : (j2 == 1) ? t1 : (j2 == 2) ? t2 :
                                     (j2 == 3) ? t3 : (j2 == 4) ? t4 : (j2 == 5) ? t5 :
                                     (j2 == 6) ? t6 : t7;
                    *(uint*)(dstb + off) = val;
                }
            }
        }
    }
    __syncthreads();

    // ---------- GEMM1: hdn = w1 @ P, 128x128x160 ----------
    f32x4 acc[2][8];
    #pragma unroll
    for (int i = 0; i < 2; ++i)
        #pragma unroll
        for (int jj = 0; jj < 8; ++jj) acc[i][jj] = (f32x4){0.f, 0.f, 0.f, 0.f};

    #pragma unroll
    for (int ct = 0; ct < 8; ++ct) {
        const int p = ct * 16 + lr;
        const char* base = PtL + p * PT_STRIDE + lk * 16;
        short8 bfrag[5];
        #pragma unroll
        for (int ks = 0; ks < 5; ++ks)
            bfrag[ks] = *(const short8*)(base + ks * 64);
        #pragma unroll
        for (int ks = 0; ks < 5; ++ks) {
            acc[0][ct] = __builtin_amdgcn_mfma_f32_16x16x32_bf16(a1[0][ks], bfrag[ks], acc[0][ct], 0, 0, 0);
            acc[1][ct] = __builtin_amdgcn_mfma_f32_16x16x32_bf16(a1[1][ks], bfrag[ks], acc[1][ct], 0, 0, 0);
        }
    }
    __syncthreads();   // Pt reads done -> reuse U as Ht

    // ---------- bias+relu -> Ht[p][hd] bf16 ----------
    #pragma unroll
    for (int rt = 0; rt < 2; ++rt) {
        const int hd0 = wid * 32 + rt * 16 + lk * 4;   // C/D row = (lane>>4)*4 + reg
        const float4 bs = *(const float4*)(b1 + m * Hd + hd0);
        #pragma unroll
        for (int ct = 0; ct < 8; ++ct) {
            const int p = ct * 16 + lr;                // C/D col = lane&15
            const f32x4 v = acc[rt][ct];
            uint2 pk;
            pk.x = (uint)f2bf(fmaxf(v[0] + bs.x, 0.f)) |
                   ((uint)f2bf(fmaxf(v[1] + bs.y, 0.f)) << 16);
            pk.y = (uint)f2bf(fmaxf(v[2] + bs.z, 0.f)) |
                   ((uint)f2bf(fmaxf(v[3] + bs.w, 0.f)) << 16);
            *(uint2*)(HtL + p * HT_STRIDE + hd0 * 2) = pk;
        }
    }
    __syncthreads();

    // ---------- GEMM2: dx = w2 @ hdn, 16x128x128 ----------
    f32x4 acc2[2];
    #pragma unroll
    for (int jj = 0; jj < 2; ++jj) {
        const int ct = wid * 2 + jj;
        const int p  = ct * 16 + lr;
        const char* base = HtL + p * HT_STRIDE + lk * 16;
        short8 bb[4];
        #pragma unroll
        for (int ks = 0; ks < 4; ++ks)
            bb[ks] = *(const short8*)(base + ks * 64);
        f32x4 a = (f32x4){0.f, 0.f, 0.f, 0.f};
        #pragma unroll
        for (int ks = 0; ks < 4; ++ks)
            a = __builtin_amdgcn_mfma_f32_16x16x32_bf16(a2[ks], bb[ks], a, 0, 0, 0);
        acc2[jj] = a;
    }
    __syncthreads();   // Ht reads done -> reuse U as dxT

    // ---------- epilogue: dxT stage -> contiguous 512B out writes ----------
    const float4 b2v = *(const float4*)(b2 + m * Cn + lk * 4);
    float (*dxT)[132] = (float(*)[132])U;   // 16 x 132 f32 (8448 B)
    {
        const float bsv[4] = {b2v.x, b2v.y, b2v.z, b2v.w};
        #pragma unroll
        for (int jj = 0; jj < 2; ++jj) {
            const int px = (wid * 2 + jj) * 16 + lr;
            #pragma unroll
            for (int rr2 = 0; rr2 < 4; ++rr2)
                dxT[lk * 4 + rr2][px] = acc2[jj][rr2] + bsv[rr2];
        }
    }
    __syncthreads();
    {
        const int c = tid >> 4, iq = tid & 15;
        const int px0 = 8 * iq;
        const float4 d0 = *(const float4*)&dxT[c][px0];
        const float4 d1 = *(const float4*)&dxT[c][px0 + 4];
        const size_t idx = ((size_t)(b * MCn + m * Cn + c)) * 1024 + p0 + px0;
        const float4 x0 = *(const float4*)(x + idx);
        const float4 x1 = *(const float4*)(x + idx + 4);
        float4 r0, r1;
        r0.x = x0.x + d0.x; r0.y = x0.y + d0.y; r0.z = x0.z + d0.z; r0.w = x0.w + d0.w;
        r1.x = x1.x + d1.x; r1.y = x1.y + d1.y; r1.z = x1.z + d1.z; r1.w = x1.w + d1.w;
        *(float4*)(out + idx)     = r0;
        *(float4*)(out + idx + 4) = r1;
    }
}

// ---------------------------------------------------------------------------
// fallback (round 6 verbatim): used when ws_size < WS_NEED
// ---------------------------------------------------------------------------
__global__ __launch_bounds__(NT, 4)
void nca_mfma_f32src(const float* __restrict__ x,  const float* __restrict__ w1,
                     const float* __restrict__ b1, const float* __restrict__ w2,
                     const float* __restrict__ b2, float* __restrict__ out)
{
    __shared__ __align__(16) char U[NP * PT_STRIDE + 16];
    char* const PtL = U;
    char* const HtL = U;

    const int tid  = threadIdx.x;
    const int lane = tid & 63;
    const int wid  = tid >> 6;
    const int lr   = lane & 15;
    const int lk   = lane >> 4;

    const int bid = blockIdx.x;
    const int xcd = bid & 7;
    const int jb  = bid >> 3;
    const int m   = jb & 63;
    const int g   = (jb >> 6) * 8 + xcd;
    const int b   = g >> 3;
    const int p0  = (g & 7) * NP;

    if (tid <= NP) {
        char* z = PtL + tid * PT_STRIDE + (tid < NP ? 288 : 0);
        *(int4*)z = (int4){0, 0, 0, 0};
    }

    short8 a1[2][5];
    #pragma unroll
    for (int rt = 0; rt < 2; ++rt) {
        const int row = wid * 32 + rt * 16 + lr;
        const float* wr = w1 + (m * Hd + row) * K9;
        #pragma unroll
        for (int ks = 0; ks < 5; ++ks) {
            const int k0 = ks * 32 + lk * 8;
            short8 t;
            if (k0 < K9) {
                const float4 f0 = *(const float4*)(wr + k0);
                const float4 f1 = *(const float4*)(wr + k0 + 4);
                t[0] = (short)f2bf(f0.x); t[1] = (short)f2bf(f0.y);
                t[2] = (short)f2bf(f0.z); t[3] = (short)f2bf(f0.w);
                t[4] = (short)f2bf(f1.x); t[5] = (short)f2bf(f1.y);
                t[6] = (short)f2bf(f1.z); t[7] = (short)f2bf(f1.w);
            } else t = (short8){0,0,0,0,0,0,0,0};
            a1[rt][ks] = t;
        }
    }
    short8 a2[4];
    #pragma unroll
    for (int ks = 0; ks < 4; ++ks) {
        const float* wr = w2 + (m * Cn + lr) * Hd + ks * 32 + lk * 8;
        const float4 f0 = *(const float4*)(wr);
        const float4 f1 = *(const float4*)(wr + 4);
        short8 t;
        t[0] = (short)f2bf(f0.x); t[1] = (short)f2bf(f0.y);
        t[2] = (short)f2bf(f0.z); t[3] = (short)f2bf(f0.w);
        t[4] = (short)f2bf(f1.x); t[5] = (short)f2bf(f1.y);
        t[6] = (short)f2bf(f1.z); t[7] = (short)f2bf(f1.w);
        a2[ks] = t;
    }
    {
        const int s     = tid & 7;
        const int kpl   = (tid >> 3) & 7;
        const int r     = tid >> 6;
        const int rbase = (g & 7) * 4 + r;
        const float* xb = x + (size_t)b * (MCn * 1024);
        const unsigned long long TAB = 0xA62918405ull;
        #pragma unroll
        for (int it = 0; it < 9; ++it) {
            const int kp = it * 8 + kpl;
            float4 hv[2];
            #pragma unroll
            for (int half = 0; half < 2; ++half) {
                const int ch = m * K9 + kp * 2 + half;
                const int sh = ch >> 10;
                const int mc = ch & 1023;
                const uint nib = (uint)(TAB >> (4 * sh)) & 15u;
                const int dr = (int)(nib & 3u) - 1;
                const int dc = (int)(nib >> 2) - 1;
                const int row = rbase + dr;
                const int wb  = 4 * s + dc;
                const int wc  = min(max(wb, 0), 28);
                float4 f = {0.f, 0.f, 0.f, 0.f};
                if ((unsigned)row < 32u)
                    f = *(const float4*)(xb + (mc * 32 + row) * 32 + wc);
                if (wb < 0)       { f.w = f.z; f.z = f.y; f.y = f.x; f.x = 0.f; }
                else if (wb > 28) { f.x = f.y; f.y = f.z; f.z = f.w; f.w = 0.f; }
                hv[half] = f;
            }
            char* dst = PtL + (r * 32 + 4 * s) * PT_STRIDE + kp * 4;
            *(uint*)(dst)                 = (uint)f2bf(hv[0].x) | ((uint)f2bf(hv[1].x) << 16);
            *(uint*)(dst + PT_STRIDE)     = (uint)f2bf(hv[0].y) | ((uint)f2bf(hv[1].y) << 16);
            *(uint*)(dst + 2 * PT_STRIDE) = (uint)f2bf(hv[0].z) | ((uint)f2bf(hv[1].z) << 16);
            *(uint*)(dst + 3 * PT_STRIDE) = (uint)f2bf(hv[0].w) | ((uint)f2bf(hv[1].w) << 16);
        }
    }
    __syncthreads();

    f32x4 acc[2][8];
    #pragma unroll
    for (int i = 0; i < 2; ++i)
        #pragma unroll
        for (int jj = 0; jj < 8; ++jj) acc[i][jj] = (f32x4){0.f, 0.f, 0.f, 0.f};
    #pragma unroll
    for (int ct = 0; ct < 8; ++ct) {
        const int p = ct * 16 + lr;
        const char* base = PtL + p * PT_STRIDE + lk * 16;
        short8 bfrag[5];
        #pragma unroll
        for (int ks = 0; ks < 5; ++ks)
            bfrag[ks] = *(const short8*)(base + ks * 64);
        #pragma unroll
        for (int ks = 0; ks < 5; ++ks) {
            acc[0][ct] = __builtin_amdgcn_mfma_f32_16x16x32_bf16(a1[0][ks], bfrag[ks], acc[0][ct], 0, 0, 0);
            acc[1][ct] = __builtin_amdgcn_mfma_f32_16x16x32_bf16(a1[1][ks], bfrag[ks], acc[1][ct], 0, 0, 0);
        }
    }
    __syncthreads();
    #pragma unroll
    for (int rt = 0; rt < 2; ++rt) {
        const int hd0 = wid * 32 + rt * 16 + lk * 4;
        const float4 bs = *(const float4*)(b1 + m * Hd + hd0);
        #pragma unroll
        for (int ct = 0; ct < 8; ++ct) {
            const int p = ct * 16 + lr;
            const f32x4 v = acc[rt][ct];
            uint2 pk;
            pk.x = (uint)f2bf(fmaxf(v[0] + bs.x, 0.f)) |
                   ((uint)f2bf(fmaxf(v[1] + bs.y, 0.f)) << 16);
            pk.y = (uint)f2bf(fmaxf(v[2] + bs.z, 0.f)) |
                   ((uint)f2bf(fmaxf(v[3] + bs.w, 0.f)) << 16);
            *(uint2*)(HtL + p * HT_STRIDE + hd0 * 2) = pk;
        }
    }
    __syncthreads();
    f32x4 acc2[2];
    #pragma unroll
    for (int jj = 0; jj < 2; ++jj) {
        const int ct = wid * 2 + jj;
        const int p  = ct * 16 + lr;
        const char* base = HtL + p * HT_STRIDE + lk * 16;
        short8 bb[4];
        #pragma unroll
        for (int ks = 0; ks < 4; ++ks)
            bb[ks] = *(const short8*)(base + ks * 64);
        f32x4 a = (f32x4){0.f, 0.f, 0.f, 0.f};
        #pragma unroll
        for (int ks = 0; ks < 4; ++ks)
            a = __builtin_amdgcn_mfma_f32_16x16x32_bf16(a2[ks], bb[ks], a, 0, 0, 0);
        acc2[jj] = a;
    }
    const float4 b2v = *(const float4*)(b2 + m * Cn + lk * 4);
    const float bsv[4] = {b2v.x, b2v.y, b2v.z, b2v.w};
    #pragma unroll
    for (int jj = 0; jj < 2; ++jj) {
        const int ct = wid * 2 + jj;
        const int gp = p0 + ct * 16 + lr;
        #pragma unroll
        for (int r = 0; r < 4; ++r) {
            const int c   = lk * 4 + r;
            const size_t idx = ((size_t)(b * MCn + m * Cn + c)) * 1024 + gp;
            out[idx] = x[idx] + acc2[jj][r] + bsv[r];
        }
    }
}

extern "C" void kernel_launch(void* const* d_in, const int* in_sizes, int n_in,
                              void* d_out, int out_size, void* d_ws, size_t ws_size,
                              hipStream_t stream)
{
    const float* x  = (const float*)d_in[0];
    const float* w1 = (const float*)d_in[1];
    const float* b1 = (const float*)d_in[2];
    const float* w2 = (const float*)d_in[3];
    const float* b2 = (const float*)d_in[4];
    float* out = (float*)d_out;
    const int grid = Mn * (Bn * 1024 / NP);   // 8192

    if (ws_size >= WS_NEED) {
        ushort* xbf  = (ushort*)d_ws;
        ushort* w1bf = (ushort*)((char*)d_ws + XBF_BYTES);
        ushort* w2bf = w1bf + W1_ELEMS;
        prep_x<<<Bn * MCn, 256, 0, stream>>>(x, xbf);
        prep_w<<<(int)((W1_ELEMS + W2_ELEMS) / 4 / 256), 256, 0, stream>>>(w1, w2, w1bf, w2bf);
        nca_mfma_bf16<<<grid, NT, 0, stream>>>(x, xbf, w1bf, b1, w2bf, b2, out);
    } else {
        nca_mfma_f32src<<<grid, NT, 0, stream>>>(x, w1, b1, w2, b2, out);
    }
}